// Round 1
// baseline (222.493 us; speedup 1.0000x reference)
//
#include <hip/hip_runtime.h>

// Factorization:
//   co_orbit[d,c] == (d != c)  ->  sum_c x[..,c] * W[.., co[d,c]]
//        = x[..,d]*(W0 - W1) + S*W1,  S = sum_c x[..,c]
//   out[b,i,o,d] = sum_{j,k} Wd[o,k,sp[i,j]] * x[b,j,k,d]
//                + sum_{j,k} W1[o,k,sp[i,j]] * S[b,j,k]  + bias[o]
//
// Prep kernel repacks weight (o,k,s,c) -> Wd[s][k][o], W1[s][k][o]
// (o fastest => coalesced reads across the wave in the main loop).

#define NSP 24

// idx = s*4096 + k*64 + o, total 24*64*64 = 98304 elements
__global__ __launch_bounds__(256) void prep_kernel(const float* __restrict__ weight,
                                                   float* __restrict__ Wd,
                                                   float* __restrict__ W1) {
    int idx = blockIdx.x * 256 + threadIdx.x;
    int o = idx & 63;
    int k = (idx >> 6) & 63;
    int s = idx >> 12;
    const float* wp = weight + (((o * 64 + k) * NSP + s) * 2);
    float w0 = wp[0], w1 = wp[1];
    Wd[idx] = w0 - w1;
    W1[idx] = w1;
}

__global__ __launch_bounds__(384) void main_kernel(const float* __restrict__ x,
                                                   const float* __restrict__ Wd,
                                                   const float* __restrict__ W1,
                                                   const float* __restrict__ bias,
                                                   const int* __restrict__ sp_orbit,
                                                   float* __restrict__ out) {
    __shared__ float xs[24 * 64 * 6];   // raw copy of x[b]: [j][k][c], 36 KB
    __shared__ float Ss[24 * 64];       // S[j][k] = sum_c xs[j][k][c], 6 KB
    __shared__ int spi[24];

    const int tid = threadIdx.x;
    const int bid = blockIdx.x;
    const int i = bid % 24;
    const int b = bid / 24;

    // stage x[b] (9216 contiguous floats = 2304 float4), 6 float4/thread, coalesced
    {
        const float4* xg = (const float4*)(x + b * 9216);
        float4* xs4 = (float4*)xs;
        #pragma unroll
        for (int u = 0; u < 6; ++u) xs4[tid + u * 384] = xg[tid + u * 384];
    }
    if (tid < 24) spi[tid] = sp_orbit[i * 24 + tid];
    __syncthreads();

    // color-sum S[j][k]
    for (int idx = tid; idx < 1536; idx += 384) {
        const float* p = xs + idx * 6;
        Ss[idx] = ((p[0] + p[1]) + (p[2] + p[3])) + (p[4] + p[5]);
    }
    __syncthreads();

    const int o = tid & 63;   // lane  -> coalesced weight reads
    const int d = tid >> 6;   // wave id (0..5)

    float acc1 = 0.f, acc2 = 0.f;
    for (int j = 0; j < 24; ++j) {
        const int s = spi[j];
        const float* __restrict__ wd = Wd + s * 4096 + o;
        const float* __restrict__ w1 = W1 + s * 4096 + o;
        const float* __restrict__ xj = xs + j * 384 + d;  // broadcast within wave
        const float* __restrict__ sj = Ss + j * 64;       // broadcast within wave
        #pragma unroll 8
        for (int k = 0; k < 64; ++k) {
            acc1 = fmaf(xj[k * 6], wd[k * 64], acc1);
            acc2 = fmaf(sj[k],     w1[k * 64], acc2);
        }
    }

    out[(b * 24 + i) * 384 + o * 6 + d] = acc1 + acc2 + bias[o];
}

extern "C" void kernel_launch(void* const* d_in, const int* in_sizes, int n_in,
                              void* d_out, int out_size, void* d_ws, size_t ws_size,
                              hipStream_t stream) {
    const float* x      = (const float*)d_in[0];
    const float* weight = (const float*)d_in[1];
    const float* bias   = (const float*)d_in[2];
    const int*   sp     = (const int*)d_in[3];
    // d_in[4] = co_orbit: structure (d != c) is folded into the factorization.

    float* Wd = (float*)d_ws;          // 98304 floats
    float* W1 = Wd + 98304;            // 98304 floats  (total 768 KB of ws)

    prep_kernel<<<384, 256, 0, stream>>>(weight, Wd, W1);
    main_kernel<<<1536, 384, 0, stream>>>(x, Wd, W1, bias, sp, (float*)d_out);
}

// Round 2
// 97.032 us; speedup vs baseline: 2.2930x; 2.2930x over previous
//
#include <hip/hip_runtime.h>

// Factorization: co_orbit[d,c] == (d != c)  =>
//   out[b,i,o,d] = sum_{j,k} (W0-W1)[sp[i,j],k,o] * x[b,j,k,d]
//                + sum_{j,k}  W1[sp[i,j],k,o]     * S[b,j,k]   + bias[o]
// Cast as ONE bf16 GEMM:  C[m][n] = sum_kk A2[m][kk] * B2t[n][kk]
//   m = i*64+o  (M=1536)
//   n = b*6+d   (N=384)
//   kk = p*1536 + j*64 + k  (K=3072):
//     A2[m][p=0,j,k] = (W0-W1)[sp[i,j],k,o]   A2[m][p=1,j,k] = W1[sp[i,j],k,o]
//     B2t[n][p=0,j,k] = x[b,j,k,d]            B2t[n][p=1,j,k] = S[b,j,k]
// Both stored row-major with kk fastest (B^T-GEMM form).

typedef short bf16x8 __attribute__((ext_vector_type(8)));
typedef float f32x4 __attribute__((ext_vector_type(4)));

static __device__ inline short f2bf(float f) {
    unsigned u = __builtin_bit_cast(unsigned, f);
    unsigned r = (u + 0x7fffu + ((u >> 16) & 1u)) >> 16;
    return (short)r;
}

#define MFMA16(a, b, c) __builtin_amdgcn_mfma_f32_16x16x32_bf16(a, b, c, 0, 0, 0)

// ---------------- prep A: gather weight -> A2 [1536][3072] bf16 ----------------
// One block per (i,j). s = sp[i,j]. Reads weight[o,k,s,{0,1}], writes two
// 64-col strips (p=0 at col j*64, p=1 at col 1536+j*64) for rows i*64..i*64+63.
__global__ __launch_bounds__(256) void prepA_kernel(const float* __restrict__ weight,
                                                    const int* __restrict__ sp,
                                                    short* __restrict__ A2) {
    __shared__ short Td[64 * 64];  // (W0-W1)[k][o] -> stored [o][k]
    __shared__ short T1[64 * 64];

    const int bi = blockIdx.x;
    const int i = bi / 24, j = bi % 24;
    const int s = sp[i * 24 + j];
    const int tid = threadIdx.x;

    // load phase: thread (o = tid>>2, kb = (tid&3)*16) reads 16 (w0,w1) pairs
    {
        const int o = tid >> 2;
        const int kb = (tid & 3) << 4;
        for (int k = kb; k < kb + 16; ++k) {
            const float2 w = *(const float2*)(weight + ((size_t)((o * 64 + k) * 24 + s) << 1));
            Td[o * 64 + k] = f2bf(w.x - w.y);
            T1[o * 64 + k] = f2bf(w.y);
        }
    }
    __syncthreads();

    // write phase: lanes along k => 128B coalesced segments per (o, array)
    {
        const int o2 = tid >> 3;      // 0..31
        const int seg = tid & 7;      // 0..7
        #pragma unroll
        for (int u = 0; u < 2; ++u) {
            const int o = o2 + u * 32;
            const bf16x8 vd = *(const bf16x8*)&Td[o * 64 + seg * 8];
            const bf16x8 v1 = *(const bf16x8*)&T1[o * 64 + seg * 8];
            *(bf16x8*)&A2[(size_t)(i * 64 + o) * 3072 + j * 64 + seg * 8] = vd;
            *(bf16x8*)&A2[(size_t)(i * 64 + o) * 3072 + 1536 + j * 64 + seg * 8] = v1;
        }
    }
}

// ---------------- prep B: x -> B2t [384][3072] bf16 ----------------
// idx = n*3072 + kk, n = b*6+d. Block = 256 consecutive kk (p uniform/block).
__global__ __launch_bounds__(256) void prepB_kernel(const float* __restrict__ x,
                                                    short* __restrict__ B2t) {
    const int bi = blockIdx.x;
    const int n = bi / 12;
    const int kk = (bi % 12) * 256 + threadIdx.x;
    const int b = n / 6;
    const int d = n - b * 6;
    const float* xb = x + (size_t)b * 9216;

    float v;
    if (kk < 1536) {
        v = xb[kk * 6 + d];
    } else {
        const int jk = kk - 1536;
        const float2 p0 = *(const float2*)(xb + jk * 6);
        const float2 p1 = *(const float2*)(xb + jk * 6 + 2);
        const float2 p2 = *(const float2*)(xb + jk * 6 + 4);
        v = ((p0.x + p0.y) + (p1.x + p1.y)) + (p2.x + p2.y);
    }
    B2t[(size_t)n * 3072 + kk] = f2bf(v);
}

// ---------------- GEMM: C = A2 * B2t^T, M=1536 N=384 K=3072 ----------------
// 64x64 tile, 256 threads = 4 waves in 2x2, each wave 32x32 via 2x2 16x16x32.
#define LDK 72  // 64 + 8 pad: row stride 144B -> conflict-free b128 ops

__global__ __launch_bounds__(256) void gemm_kernel(const short* __restrict__ A2,
                                                   const short* __restrict__ B2t,
                                                   const float* __restrict__ bias,
                                                   float* __restrict__ out) {
    __shared__ short As[64 * LDK];
    __shared__ short Bs[64 * LDK];

    const int tid = threadIdx.x;
    const int m0 = (int)blockIdx.x * 64;   // 24 tiles
    const int n0 = (int)blockIdx.y * 64;   // 6 tiles

    const int lane = tid & 63;
    const int wid = tid >> 6;
    const int wr = wid >> 1, wc = wid & 1;
    const int lr = lane & 15;
    const int lk = (lane >> 4) * 8;

    const int srow = tid >> 3;   // 0..31 (staging row base)
    const int sseg = tid & 7;    // 0..7  (staging 16B segment)

    f32x4 acc00 = {0.f, 0.f, 0.f, 0.f};
    f32x4 acc01 = {0.f, 0.f, 0.f, 0.f};
    f32x4 acc10 = {0.f, 0.f, 0.f, 0.f};
    f32x4 acc11 = {0.f, 0.f, 0.f, 0.f};

    for (int kt = 0; kt < 48; ++kt) {
        const int kb = kt * 64;
        #pragma unroll
        for (int u = 0; u < 2; ++u) {
            const int row = srow + u * 32;
            *(bf16x8*)&As[row * LDK + sseg * 8] =
                *(const bf16x8*)(A2 + (size_t)(m0 + row) * 3072 + kb + sseg * 8);
            *(bf16x8*)&Bs[row * LDK + sseg * 8] =
                *(const bf16x8*)(B2t + (size_t)(n0 + row) * 3072 + kb + sseg * 8);
        }
        __syncthreads();

        #pragma unroll
        for (int kc = 0; kc < 2; ++kc) {
            const bf16x8 a0 = *(const bf16x8*)&As[(wr * 32 + lr) * LDK + kc * 32 + lk];
            const bf16x8 a1 = *(const bf16x8*)&As[(wr * 32 + 16 + lr) * LDK + kc * 32 + lk];
            const bf16x8 b0 = *(const bf16x8*)&Bs[(wc * 32 + lr) * LDK + kc * 32 + lk];
            const bf16x8 b1 = *(const bf16x8*)&Bs[(wc * 32 + 16 + lr) * LDK + kc * 32 + lk];
            acc00 = MFMA16(a0, b0, acc00);
            acc01 = MFMA16(a0, b1, acc01);
            acc10 = MFMA16(a1, b0, acc10);
            acc11 = MFMA16(a1, b1, acc11);
        }
        __syncthreads();
    }

    // epilogue: C/D layout col = lane&15, row = (lane>>4)*4 + reg  [m89-verified]
    const int rbase = (lane >> 4) * 4;
    const int cbase = lane & 15;
    #pragma unroll
    for (int mi = 0; mi < 2; ++mi) {
        #pragma unroll
        for (int ni = 0; ni < 2; ++ni) {
            const f32x4 a = (mi == 0) ? (ni == 0 ? acc00 : acc01)
                                      : (ni == 0 ? acc10 : acc11);
            const int col = n0 + wc * 32 + ni * 16 + cbase;
            const int b = col / 6;
            const int d = col - b * 6;
            #pragma unroll
            for (int r = 0; r < 4; ++r) {
                const int row = m0 + wr * 32 + mi * 16 + rbase + r;
                const int i = row >> 6;
                const int o = row & 63;
                out[((b * 24 + i) * 384) + o * 6 + d] = a[r] + bias[o];
            }
        }
    }
}

extern "C" void kernel_launch(void* const* d_in, const int* in_sizes, int n_in,
                              void* d_out, int out_size, void* d_ws, size_t ws_size,
                              hipStream_t stream) {
    const float* x      = (const float*)d_in[0];
    const float* weight = (const float*)d_in[1];
    const float* bias   = (const float*)d_in[2];
    const int*   sp     = (const int*)d_in[3];
    // d_in[4] = co_orbit: folded into the (d != c) factorization.

    short* A2  = (short*)d_ws;                       // 1536*3072 bf16 = 9.44 MB
    short* B2t = A2 + (size_t)1536 * 3072;           //  384*3072 bf16 = 2.36 MB

    prepA_kernel<<<576, 256, 0, stream>>>(weight, sp, A2);
    prepB_kernel<<<4608, 256, 0, stream>>>(x, B2t);
    gemm_kernel<<<dim3(24, 6), 256, 0, stream>>>(A2, B2t, bias, (float*)d_out);
}

// Round 3
// 33.424 us; speedup vs baseline: 6.6567x; 2.9030x over previous
//
#include <hip/hip_runtime.h>

// co_orbit[d,c] == (d != c)  =>
//   out[b,i,o,d] = sum_{j,k} Wd[sp[i,j]][o][k] * x[b,j,k,d]
//                + sum_{j,k} W1[sp[i,j]][o][k] * S[b,j,k]   + bias[o]
// One GEMM  C[m=i*64+o][n=b*6+d] = sum_kk A[m][kk]*B[n][kk],  K=3072:
//   kk = p*1536 + j*64 + k;  A[m][p,j,k] = Wboth[p][sp[i,j]][o][k] (gathered
//   on the fly, no A materialization);  B[n][p=0,j,k]=x[b,j,k,d], [p=1]=S[b,j,k].
// GEMM: 32x32 tiles (576 blocks), 4 waves with PRIVATE K-quarters + private
// LDS panels -> no barriers in K-loop; LDS cross-wave reduce at the end.

typedef short bf16x8 __attribute__((ext_vector_type(8)));
typedef float f32x4 __attribute__((ext_vector_type(4)));

static __device__ inline short f2bf(float f) {
    unsigned u = __builtin_bit_cast(unsigned, f);
    unsigned r = (u + 0x7fffu + ((u >> 16) & 1u)) >> 16;
    return (short)r;
}

#define MFMA16(a, b, c) __builtin_amdgcn_mfma_f32_16x16x32_bf16(a, b, c, 0, 0, 0)

// ---------------- prep: blocks 0..23 weight repack, 24..87 B build ----------------
__global__ __launch_bounds__(256) void prep_kernel(const float* __restrict__ weight,
                                                   const float* __restrict__ x,
                                                   short* __restrict__ Wboth,
                                                   short* __restrict__ B2t) {
    __shared__ float xs[9216];
    __shared__ float Ss[1536];
    const int t = threadIdx.x;
    const int blk = blockIdx.x;

    if (blk < 24) {
        // Wboth[p][s][o][k] <- weight[o][k][s][c]:  p0 = w0-w1, p1 = w1
        const int s = blk;
        const int o = t >> 2;
        const int k0 = (t & 3) << 4;
        bf16x8 vd0, vd1, v10, v11;
        #pragma unroll
        for (int e = 0; e < 8; ++e) {
            const float2 wa = *(const float2*)(weight + ((size_t)((o * 64 + k0 + e) * 24 + s) << 1));
            const float2 wb = *(const float2*)(weight + ((size_t)((o * 64 + k0 + 8 + e) * 24 + s) << 1));
            vd0[e] = f2bf(wa.x - wa.y);  v10[e] = f2bf(wa.y);
            vd1[e] = f2bf(wb.x - wb.y);  v11[e] = f2bf(wb.y);
        }
        short* pd = Wboth + ((size_t)s * 64 + o) * 64 + k0;
        short* p1 = Wboth + ((size_t)(24 + s) * 64 + o) * 64 + k0;
        *(bf16x8*)pd = vd0;  *(bf16x8*)(pd + 8) = vd1;
        *(bf16x8*)p1 = v10;  *(bf16x8*)(p1 + 8) = v11;
    } else {
        // B2t[n=b*6+d][kk]:  kk<1536 -> x[b][jk][d];  else S[b][jk]
        const int b = blk - 24;
        const float4* xg = (const float4*)(x + (size_t)b * 9216);
        float4* x4 = (float4*)xs;
        #pragma unroll
        for (int u = 0; u < 9; ++u) x4[t + u * 256] = xg[t + u * 256];
        __syncthreads();
        #pragma unroll
        for (int u = 0; u < 6; ++u) {
            const int idx = t + u * 256;
            const float* p = xs + idx * 6;
            Ss[idx] = ((p[0] + p[1]) + (p[2] + p[3])) + (p[4] + p[5]);
        }
        __syncthreads();
        #pragma unroll
        for (int u = 0; u < 9; ++u) {
            const int cid = t + u * 256;       // 0..2303 = 6 rows x 384 chunks
            const int d = cid / 384;
            const int c8 = cid - d * 384;
            const int kk = c8 * 8;
            bf16x8 v;
            if (kk < 1536) {
                #pragma unroll
                for (int e = 0; e < 8; ++e) v[e] = f2bf(xs[(kk + e) * 6 + d]);
            } else {
                const int jk = kk - 1536;
                #pragma unroll
                for (int e = 0; e < 8; ++e) v[e] = f2bf(Ss[jk + e]);
            }
            *(bf16x8*)&B2t[(size_t)(b * 6 + d) * 3072 + kk] = v;
        }
    }
}

// ---------------- GEMM: M=1536 N=384 K=3072, 32x32 tile, wave-split K ----------------
#define LDK 88  // 176B row stride: 16B-aligned rows, uniform bank-quad spread for b128

__global__ __launch_bounds__(256) void gemm_kernel(const short* __restrict__ Wboth,
                                                   const short* __restrict__ B2t,
                                                   const float* __restrict__ bias,
                                                   const int* __restrict__ sp,
                                                   float* __restrict__ out) {
    __shared__ __align__(16) short As[4][32][LDK];
    __shared__ __align__(16) short Bs[4][32][LDK];

    const int tid = threadIdx.x;
    const int lane = tid & 63;
    const int w = tid >> 6;

    const int bx = (int)blockIdx.x;
    const int mt = bx % 48;
    const int nt = bx / 48;
    const int m0 = mt * 32;  (void)m0;
    const int n0 = nt * 32;
    const int i  = mt >> 1;
    const int o0 = (mt & 1) * 32;

    // wave w: p = w>>1, j in [jbase, jbase+12)
    const int p = w >> 1;
    const int jbase = (w & 1) * 12;

    int sidx[12];
    #pragma unroll
    for (int t_ = 0; t_ < 12; ++t_) sidx[t_] = sp[i * 24 + jbase + t_];

    const int srow = lane >> 1;          // staged row 0..31
    const int sk0  = (lane & 1) * 32;    // k-half

    const short* bsrc = B2t + (size_t)(n0 + srow) * 3072 + p * 1536 + jbase * 64 + sk0;
    const int aoff = (o0 + srow) * 64 + sk0;
    const size_t pbase = (size_t)p * 24 * 4096;

    short* awr = &As[w][srow][sk0];
    short* bwr = &Bs[w][srow][sk0];

    const int lr = lane & 15;
    const int lk = (lane >> 4) * 8;

    f32x4 acc[2][2] = {{{0.f,0.f,0.f,0.f},{0.f,0.f,0.f,0.f}},
                       {{0.f,0.f,0.f,0.f},{0.f,0.f,0.f,0.f}}};

    bf16x8 rA[2][4], rB[2][4];
    {   // prologue: prefetch step 0
        const short* ap = Wboth + pbase + (size_t)sidx[0] * 4096 + aoff;
        #pragma unroll
        for (int u = 0; u < 4; ++u) {
            rA[0][u] = *(const bf16x8*)(ap + u * 8);
            rB[0][u] = *(const bf16x8*)(bsrc + u * 8);
        }
    }

    #pragma unroll
    for (int t_ = 0; t_ < 12; ++t_) {
        const int cur = t_ & 1;
        const int nxt = cur ^ 1;
        #pragma unroll
        for (int u = 0; u < 4; ++u) {
            *(bf16x8*)(awr + u * 8) = rA[cur][u];
            *(bf16x8*)(bwr + u * 8) = rB[cur][u];
        }
        if (t_ < 11) {  // prefetch next panel while current computes
            const short* ap = Wboth + pbase + (size_t)sidx[t_ + 1] * 4096 + aoff;
            const short* bp = bsrc + (t_ + 1) * 64;
            #pragma unroll
            for (int u = 0; u < 4; ++u) {
                rA[nxt][u] = *(const bf16x8*)(ap + u * 8);
                rB[nxt][u] = *(const bf16x8*)(bp + u * 8);
            }
        }
        #pragma unroll
        for (int kc = 0; kc < 2; ++kc) {
            const bf16x8 a0 = *(const bf16x8*)&As[w][lr][kc * 32 + lk];
            const bf16x8 a1 = *(const bf16x8*)&As[w][16 + lr][kc * 32 + lk];
            const bf16x8 b0 = *(const bf16x8*)&Bs[w][lr][kc * 32 + lk];
            const bf16x8 b1 = *(const bf16x8*)&Bs[w][16 + lr][kc * 32 + lk];
            acc[0][0] = MFMA16(a0, b0, acc[0][0]);
            acc[0][1] = MFMA16(a0, b1, acc[0][1]);
            acc[1][0] = MFMA16(a1, b0, acc[1][0]);
            acc[1][1] = MFMA16(a1, b1, acc[1][1]);
        }
    }

    // cross-wave reduce: Red[w][lane][16] fp32 (16KB, reuses As region)
    __syncthreads();
    float* Red = (float*)&As[0][0][0];
    #pragma unroll
    for (int mi = 0; mi < 2; ++mi)
        #pragma unroll
        for (int ni = 0; ni < 2; ++ni)
            *(f32x4*)&Red[((w * 64 + lane) * 16) + mi * 8 + ni * 4] = acc[mi][ni];
    __syncthreads();

    const int l  = tid & 63;
    const int mi = (tid >> 7) & 1;
    const int ni = (tid >> 6) & 1;
    const int fb = mi * 8 + ni * 4;
    f32x4 sum = *(const f32x4*)&Red[(l * 16) + fb];
    #pragma unroll
    for (int ww = 1; ww < 4; ++ww) sum += *(const f32x4*)&Red[((ww * 64 + l) * 16) + fb];

    // C/D layout: col = lane&15, row = (lane>>4)*4 + r  [round-2-verified]
    const int col = n0 + ni * 16 + (l & 15);
    const int b = col / 6;
    const int d = col - b * 6;
    const int rb = (l >> 4) * 4;
    #pragma unroll
    for (int r = 0; r < 4; ++r) {
        const int o = o0 + mi * 16 + rb + r;
        out[((size_t)(b * 24 + i)) * 384 + o * 6 + d] = sum[r] + bias[o];
    }
}

extern "C" void kernel_launch(void* const* d_in, const int* in_sizes, int n_in,
                              void* d_out, int out_size, void* d_ws, size_t ws_size,
                              hipStream_t stream) {
    const float* x      = (const float*)d_in[0];
    const float* weight = (const float*)d_in[1];
    const float* bias   = (const float*)d_in[2];
    const int*   sp     = (const int*)d_in[3];
    // d_in[4] = co_orbit: folded into the (d != c) factorization.

    short* Wboth = (short*)d_ws;                    // 2*24*64*64 bf16 = 384 KB
    short* B2t   = Wboth + (size_t)2 * 24 * 4096;   // 384*3072 bf16  = 2.36 MB

    prep_kernel<<<88, 256, 0, stream>>>(weight, x, Wboth, B2t);
    gemm_kernel<<<576, 256, 0, stream>>>(Wboth, B2t, bias, sp, (float*)d_out);
}

// Round 4
// 26.700 us; speedup vs baseline: 8.3331x; 1.2518x over previous
//
#include <hip/hip_runtime.h>

// co_orbit[d,c] == (d != c)  =>
//   out[b,i,o,d] = sum_{j,k} Wd[sp[i,j]][o][k] * x[b,j,k,d]
//                + sum_{j,k} W1[sp[i,j]][o][k] * S[b,j,k]   + bias[o]
// One GEMM  C[m=i*64+o][n=b*6+d] = sum_kk A[m][kk]*B[n][kk],  K=3072,
//   kk = p*1536 + j*64 + k;  A gathered on the fly via sp from Wfrag panels.
//
// Both operands are stored in MFMA FRAGMENT ORDER: each 16(row)x32(k) subtile
// is 512 bf16 laid out as lane*8+e with lane=(row&15)|(((k>>3)&3)<<4), e=k&7
// (exactly the 16x16x32 A/B fragment a wave needs). K-loop = pure
// global_load_dwordx4 + MFMA: no LDS, no barriers. LDS only for the final
// cross-wave (split-K) reduction.

typedef short bf16x8 __attribute__((ext_vector_type(8)));
typedef float f32x4 __attribute__((ext_vector_type(4)));

static __device__ inline short f2bf(float f) {
    unsigned u = __builtin_bit_cast(unsigned, f);
    unsigned r = (u + 0x7fffu + ((u >> 16) & 1u)) >> 16;
    return (short)r;
}

#define MFMA16(a, b, c) __builtin_amdgcn_mfma_f32_16x16x32_bf16(a, b, c, 0, 0, 0)

// ---------------- prep: blocks 0..23 weight repack, 24..87 B build ----------------
// Wfrag[p][s]: 64x64 panel in frag order: subtile (og=o>>4, kc=k>>5) at
//   (og*2+kc)*512, elem at lane*8+(k&7), lane=(o&15)|(((k>>3)&3)<<4)
// Bfrag: [384 n][3072 kk] in frag order: subtile (ng=n>>4, kc2=kk>>5) at
//   (ng*96+kc2)*512, same intra-subtile layout.
__global__ __launch_bounds__(256) void prep_kernel(const float* __restrict__ weight,
                                                   const float* __restrict__ x,
                                                   short* __restrict__ Wfrag,
                                                   short* __restrict__ Bfrag) {
    __shared__ float xs[9216];
    __shared__ float Ss[1536];
    const int t = threadIdx.x;
    const int blk = blockIdx.x;

    if (blk < 24) {
        const int s = blk;
        const int o = t >> 2;
        const int kq = (t & 3) << 4;      // two 8-chunks: kq, kq+8
        #pragma unroll
        for (int h = 0; h < 2; ++h) {
            const int k0 = kq + h * 8;
            bf16x8 vd, v1;
            #pragma unroll
            for (int e = 0; e < 8; ++e) {
                const float2 wv = *(const float2*)(weight + ((size_t)((o * 64 + k0 + e) * 24 + s) << 1));
                vd[e] = f2bf(wv.x - wv.y);
                v1[e] = f2bf(wv.y);
            }
            const int lane_f = (o & 15) | (((k0 >> 3) & 3) << 4);
            const int sub = ((o >> 4) * 2 + (k0 >> 5)) * 512 + lane_f * 8;
            *(bf16x8*)&Wfrag[(size_t)s * 4096 + sub] = vd;
            *(bf16x8*)&Wfrag[(size_t)(24 + s) * 4096 + sub] = v1;
        }
    } else {
        const int b = blk - 24;
        const float4* xg = (const float4*)(x + (size_t)b * 9216);
        float4* x4 = (float4*)xs;
        #pragma unroll
        for (int u = 0; u < 9; ++u) x4[t + u * 256] = xg[t + u * 256];
        __syncthreads();
        #pragma unroll
        for (int u = 0; u < 6; ++u) {
            const int idx = t + u * 256;
            const float* p = xs + idx * 6;
            Ss[idx] = ((p[0] + p[1]) + (p[2] + p[3])) + (p[4] + p[5]);
        }
        __syncthreads();
        #pragma unroll
        for (int u = 0; u < 9; ++u) {
            const int cid = t + u * 256;       // 6 d-rows x 384 8-chunks
            const int d = cid / 384;
            const int kk = (cid - d * 384) * 8;
            bf16x8 v;
            if (kk < 1536) {
                #pragma unroll
                for (int e = 0; e < 8; ++e) v[e] = f2bf(xs[(kk + e) * 6 + d]);
            } else {
                const int jk = kk - 1536;
                #pragma unroll
                for (int e = 0; e < 8; ++e) v[e] = f2bf(Ss[jk + e]);
            }
            const int n = b * 6 + d;
            const int lane_f = (n & 15) | (((kk >> 3) & 3) << 4);
            *(bf16x8*)&Bfrag[(size_t)((n >> 4) * 96 + (kk >> 5)) * 512 + lane_f * 8] = v;
        }
    }
}

// ---------------- GEMM: M=1536 N=384 K=3072, 32x32 tile, wave-split K ----------------
__global__ __launch_bounds__(256) void gemm_kernel(const short* __restrict__ Wfrag,
                                                   const short* __restrict__ Bfrag,
                                                   const float* __restrict__ bias,
                                                   const int* __restrict__ sp,
                                                   float* __restrict__ out) {
    __shared__ __align__(16) float Red[4][64][16];   // 16 KB

    const int tid = threadIdx.x;
    const int lane = tid & 63;
    const int w = tid >> 6;

    const int bx = (int)blockIdx.x;
    const int mt = bx % 48;
    const int nt = bx / 48;
    const int i  = mt >> 1;
    const int o0 = (mt & 1) * 32;
    const int n0 = nt * 32;

    const int p = w >> 1;            // K-split: wave owns p-half, j-half
    const int jbase = (w & 1) * 12;

    int sidx[12];
    #pragma unroll
    for (int t_ = 0; t_ < 12; ++t_) sidx[t_] = sp[i * 24 + jbase + t_];

    // A frag base: + f*512 for f = mi*2+kc
    const size_t abase0 = (size_t)p * 24 * 4096 + (size_t)(o0 >> 4) * 1024 + lane * 8;
    // B frag base: step t_ adds t_*1024; + ni*49152 + kc*512
    const short* bbase = Bfrag + (size_t)(n0 >> 4) * 49152 + (size_t)(p * 48 + jbase * 2) * 512 + lane * 8;

    f32x4 acc[2][2] = {{{0.f,0.f,0.f,0.f},{0.f,0.f,0.f,0.f}},
                       {{0.f,0.f,0.f,0.f},{0.f,0.f,0.f,0.f}}};

    bf16x8 rA[2][4], rB[2][4];

#define LOADSTEP(t_, buf)                                                       \
    {                                                                           \
        const short* ap = Wfrag + (size_t)sidx[t_] * 4096 + abase0;             \
        const short* bp = bbase + (t_) * 1024;                                  \
        _Pragma("unroll")                                                       \
        for (int f = 0; f < 4; ++f) {                                           \
            rA[buf][f] = *(const bf16x8*)(ap + f * 512);                        \
            rB[buf][f] = *(const bf16x8*)(bp + ((f >> 1) * 49152) + (f & 1) * 512); \
        }                                                                       \
    }

    LOADSTEP(0, 0)
    #pragma unroll
    for (int t_ = 0; t_ < 12; ++t_) {
        const int cur = t_ & 1;
        if (t_ < 11) LOADSTEP(t_ + 1, cur ^ 1)
        #pragma unroll
        for (int kc = 0; kc < 2; ++kc) {
            #pragma unroll
            for (int mi = 0; mi < 2; ++mi)
                #pragma unroll
                for (int ni = 0; ni < 2; ++ni)
                    acc[mi][ni] = MFMA16(rA[cur][mi * 2 + kc], rB[cur][ni * 2 + kc], acc[mi][ni]);
        }
    }
#undef LOADSTEP

    // cross-wave (split-K) reduction
    #pragma unroll
    for (int mi = 0; mi < 2; ++mi)
        #pragma unroll
        for (int ni = 0; ni < 2; ++ni)
            *(f32x4*)&Red[w][lane][mi * 8 + ni * 4] = acc[mi][ni];
    __syncthreads();

    const int l  = tid & 63;
    const int mi = (tid >> 7) & 1;
    const int ni = (tid >> 6) & 1;
    const int fb = mi * 8 + ni * 4;
    f32x4 sum = *(const f32x4*)&Red[0][l][fb];
    #pragma unroll
    for (int ww = 1; ww < 4; ++ww) sum += *(const f32x4*)&Red[ww][l][fb];

    // C/D layout: col = lane&15, row = (lane>>4)*4 + r  [round-2/3-verified]
    const int col = n0 + ni * 16 + (l & 15);
    const int b = col / 6;
    const int d = col - b * 6;
    const int rb = (l >> 4) * 4;
    #pragma unroll
    for (int r = 0; r < 4; ++r) {
        const int o = o0 + mi * 16 + rb + r;
        out[((size_t)(b * 24 + i)) * 384 + o * 6 + d] = sum[r] + bias[o];
    }
}

extern "C" void kernel_launch(void* const* d_in, const int* in_sizes, int n_in,
                              void* d_out, int out_size, void* d_ws, size_t ws_size,
                              hipStream_t stream) {
    const float* x      = (const float*)d_in[0];
    const float* weight = (const float*)d_in[1];
    const float* bias   = (const float*)d_in[2];
    const int*   sp     = (const int*)d_in[3];
    // d_in[4] = co_orbit: folded into the (d != c) factorization.

    short* Wfrag = (short*)d_ws;                    // 2*24*4096 bf16 = 384 KB
    short* Bfrag = Wfrag + (size_t)2 * 24 * 4096;   // 384*3072 bf16  = 2.36 MB

    prep_kernel<<<88, 256, 0, stream>>>(weight, x, Wfrag, Bfrag);
    gemm_kernel<<<576, 256, 0, stream>>>(Wfrag, Bfrag, bias, sp, (float*)d_out);
}

// Round 5
// 26.487 us; speedup vs baseline: 8.4000x; 1.0080x over previous
//
#include <hip/hip_runtime.h>

// co_orbit[d,c] == (d != c)  =>
//   out[b,i,o,d] = sum_{j,k} Wd[sp[i,j]][o][k] * x[b,j,k,d]
//                + sum_{j,k} W1[sp[i,j]][o][k] * S[b,j,k]   + bias[o]
// One GEMM  C[m=i*64+o][n=b*6+d] = sum_kk A[m][kk]*B[n][kk],  K=3072,
//   kk = p*1536 + j*64 + k;  A gathered on the fly via sp from Wfrag panels.
//
// Operands stored in MFMA FRAGMENT ORDER: each 16(row)x32(k) subtile = 512
// bf16 at lane*8+e, lane=(row&15)|(((k>>3)&3)<<4), e=k&7. K-loop = pure
// global_load_dwordx4 + MFMA: no LDS, no barriers. 8-wave split-K (K/8 per
// wave, 6 steps) -> 4.5 waves/SIMD for latency hiding; LDS 8-way reduce.

typedef short bf16x8 __attribute__((ext_vector_type(8)));
typedef float f32x4 __attribute__((ext_vector_type(4)));

static __device__ inline short f2bf(float f) {
    unsigned u = __builtin_bit_cast(unsigned, f);
    unsigned r = (u + 0x7fffu + ((u >> 16) & 1u)) >> 16;
    return (short)r;
}

#define MFMA16(a, b, c) __builtin_amdgcn_mfma_f32_16x16x32_bf16(a, b, c, 0, 0, 0)

// ---------------- prep: blocks 0..23 weight repack, 24..87 B build ----------------
__global__ __launch_bounds__(512) void prep_kernel(const float* __restrict__ weight,
                                                   const float* __restrict__ x,
                                                   short* __restrict__ Wfrag,
                                                   short* __restrict__ Bfrag) {
    __shared__ float xs[9216];
    __shared__ float Ss[1536];
    const int t = threadIdx.x;
    const int blk = blockIdx.x;

    if (blk < 24) {
        const int s = blk;
        const int o = t >> 3;             // 0..63
        const int k0 = (t & 7) << 3;      // one 8-chunk
        bf16x8 vd, v1;
        #pragma unroll
        for (int e = 0; e < 8; ++e) {
            const float2 wv = *(const float2*)(weight + ((size_t)((o * 64 + k0 + e) * 24 + s) << 1));
            vd[e] = f2bf(wv.x - wv.y);
            v1[e] = f2bf(wv.y);
        }
        const int lane_f = (o & 15) | (((k0 >> 3) & 3) << 4);
        const int sub = ((o >> 4) * 2 + (k0 >> 5)) * 512 + lane_f * 8;
        *(bf16x8*)&Wfrag[(size_t)s * 4096 + sub] = vd;
        *(bf16x8*)&Wfrag[(size_t)(24 + s) * 4096 + sub] = v1;
    } else {
        const int b = blk - 24;
        const float4* xg = (const float4*)(x + (size_t)b * 9216);
        float4* x4 = (float4*)xs;
        for (int idx = t; idx < 2304; idx += 512) x4[idx] = xg[idx];
        __syncthreads();
        #pragma unroll
        for (int u = 0; u < 3; ++u) {
            const int idx = t + u * 512;
            const float* p = xs + idx * 6;
            Ss[idx] = ((p[0] + p[1]) + (p[2] + p[3])) + (p[4] + p[5]);
        }
        __syncthreads();
        for (int cid = t; cid < 2304; cid += 512) {   // 6 d-rows x 384 8-chunks
            const int d = cid / 384;
            const int kk = (cid - d * 384) * 8;
            bf16x8 v;
            if (kk < 1536) {
                #pragma unroll
                for (int e = 0; e < 8; ++e) v[e] = f2bf(xs[(kk + e) * 6 + d]);
            } else {
                const int jk = kk - 1536;
                #pragma unroll
                for (int e = 0; e < 8; ++e) v[e] = f2bf(Ss[jk + e]);
            }
            const int n = b * 6 + d;
            const int lane_f = (n & 15) | (((kk >> 3) & 3) << 4);
            *(bf16x8*)&Bfrag[(size_t)((n >> 4) * 96 + (kk >> 5)) * 512 + lane_f * 8] = v;
        }
    }
}

// ---------------- GEMM: M=1536 N=384 K=3072, 32x32 tile, 8-wave split-K ----------------
__global__ __launch_bounds__(512, 4) void gemm_kernel(const short* __restrict__ Wfrag,
                                                      const short* __restrict__ Bfrag,
                                                      const float* __restrict__ bias,
                                                      const int* __restrict__ sp,
                                                      float* __restrict__ out) {
    __shared__ __align__(16) float Red[8][64][16];   // 32 KB

    const int tid = threadIdx.x;
    const int lane = tid & 63;
    const int w = tid >> 6;          // 0..7

    const int bx = (int)blockIdx.x;
    const int mt = bx % 48;
    const int nt = bx / 48;
    const int i  = mt >> 1;
    const int o0 = (mt & 1) * 32;
    const int n0 = nt * 32;

    const int p = w >> 2;            // K/8 split: wave owns (p, 6 j's)
    const int jbase = (w & 3) * 6;

    int sidx[6];
    #pragma unroll
    for (int t_ = 0; t_ < 6; ++t_) sidx[t_] = sp[i * 24 + jbase + t_];

    // A frag base: + f*512 for f = mi*2+kc
    const size_t abase0 = (size_t)p * 24 * 4096 + (size_t)(o0 >> 4) * 1024 + lane * 8;
    // B frag base: step t_ adds t_*1024; frag f: +(f>>1)*49152 + (f&1)*512
    const short* bbase = Bfrag + (size_t)(n0 >> 4) * 49152 + (size_t)(p * 48 + jbase * 2) * 512 + lane * 8;

    f32x4 acc[2][2] = {{{0.f,0.f,0.f,0.f},{0.f,0.f,0.f,0.f}},
                       {{0.f,0.f,0.f,0.f},{0.f,0.f,0.f,0.f}}};

    bf16x8 rA[2][4], rB[2][4];

#define LOADSTEP(t_, buf)                                                       \
    {                                                                           \
        const short* ap = Wfrag + (size_t)sidx[t_] * 4096 + abase0;             \
        const short* bp = bbase + (t_) * 1024;                                  \
        _Pragma("unroll")                                                       \
        for (int f = 0; f < 4; ++f) {                                           \
            rA[buf][f] = *(const bf16x8*)(ap + f * 512);                        \
            rB[buf][f] = *(const bf16x8*)(bp + ((f >> 1) * 49152) + (f & 1) * 512); \
        }                                                                       \
    }

    LOADSTEP(0, 0)
    #pragma unroll
    for (int t_ = 0; t_ < 6; ++t_) {
        const int cur = t_ & 1;
        if (t_ < 5) LOADSTEP(t_ + 1, cur ^ 1)
        #pragma unroll
        for (int kc = 0; kc < 2; ++kc) {
            #pragma unroll
            for (int mi = 0; mi < 2; ++mi)
                #pragma unroll
                for (int ni = 0; ni < 2; ++ni)
                    acc[mi][ni] = MFMA16(rA[cur][mi * 2 + kc], rB[cur][ni * 2 + kc], acc[mi][ni]);
        }
    }
#undef LOADSTEP

    // 8-way cross-wave (split-K) reduction
    #pragma unroll
    for (int mi = 0; mi < 2; ++mi)
        #pragma unroll
        for (int ni = 0; ni < 2; ++ni)
            *(f32x4*)&Red[w][lane][mi * 8 + ni * 4] = acc[mi][ni];
    __syncthreads();

    if (tid < 256) {
        const int l  = tid & 63;
        const int g  = tid >> 6;        // 0..3
        const int mi = g >> 1;
        const int ni = g & 1;
        const int fb = mi * 8 + ni * 4;
        f32x4 sum = *(const f32x4*)&Red[0][l][fb];
        #pragma unroll
        for (int ww = 1; ww < 8; ++ww) sum += *(const f32x4*)&Red[ww][l][fb];

        // C/D layout: col = lane&15, row = (lane>>4)*4 + r  [verified]
        const int col = n0 + ni * 16 + (l & 15);
        const int b = col / 6;
        const int d = col - b * 6;
        const int rb = (l >> 4) * 4;
        #pragma unroll
        for (int r = 0; r < 4; ++r) {
            const int o = o0 + mi * 16 + rb + r;
            out[((size_t)(b * 24 + i)) * 384 + o * 6 + d] = sum[r] + bias[o];
        }
    }
}

extern "C" void kernel_launch(void* const* d_in, const int* in_sizes, int n_in,
                              void* d_out, int out_size, void* d_ws, size_t ws_size,
                              hipStream_t stream) {
    const float* x      = (const float*)d_in[0];
    const float* weight = (const float*)d_in[1];
    const float* bias   = (const float*)d_in[2];
    const int*   sp     = (const int*)d_in[3];
    // d_in[4] = co_orbit: folded into the (d != c) factorization.

    short* Wfrag = (short*)d_ws;                    // 2*24*4096 bf16 = 384 KB
    short* Bfrag = Wfrag + (size_t)2 * 24 * 4096;   // 384*3072 bf16  = 2.36 MB

    prep_kernel<<<88, 512, 0, stream>>>(weight, x, Wfrag, Bfrag);
    gemm_kernel<<<576, 512, 0, stream>>>(Wfrag, Bfrag, bias, sp, (float*)d_out);
}

// Round 6
// 24.342 us; speedup vs baseline: 9.1405x; 1.0882x over previous
//
#include <hip/hip_runtime.h>

// co_orbit[d,c] == (d != c)  =>
//   out[b,i,o,d] = sum_{j,k} Wd[sp[i,j]][o][k] * x[b,j,k,d]      (main GEMM, K=1536)
//                + sum_{j,k} W1[sp[i,j]][o][k] * S[b,j,k]         (T[m][b], d-independent!)
//                + bias[o]
// The S-term is computed ONCE per (m,b) by a tiny GEMM (M=1536,N=64,K=1536)
// instead of being replicated across the 6 d's inside one big GEMM.
//
// All operands stored in MFMA FRAGMENT ORDER: each 16(row)x32(k) subtile = 512
// bf16 at lane*8+e, lane=(row&15)|(((k>>3)&3)<<4), e=k&7. K-loops are pure
// global_load_dwordx4 + MFMA (no LDS, no barriers); LDS only for the 8-way
// in-block split-K reduction.

typedef short bf16x8 __attribute__((ext_vector_type(8)));
typedef float f32x4 __attribute__((ext_vector_type(4)));

static __device__ inline short f2bf(float f) {
    unsigned u = __builtin_bit_cast(unsigned, f);
    unsigned r = (u + 0x7fffu + ((u >> 16) & 1u)) >> 16;
    return (short)r;
}

#define MFMA16(a, b, c) __builtin_amdgcn_mfma_f32_16x16x32_bf16(a, b, c, 0, 0, 0)

// ---------------- prep: blocks 0..23 weight repack, 24..87 B/S build ----------------
__global__ __launch_bounds__(512) void prep_kernel(const float* __restrict__ weight,
                                                   const float* __restrict__ x,
                                                   short* __restrict__ Wfrag,
                                                   short* __restrict__ BfragX,
                                                   short* __restrict__ Sfrag) {
    __shared__ float xs[9216];
    __shared__ float Ss[1536];
    const int t = threadIdx.x;
    const int blk = blockIdx.x;

    if (blk < 24) {
        const int s = blk;
        const int o = t >> 3;             // 0..63
        const int k0 = (t & 7) << 3;      // one 8-chunk
        bf16x8 vd, v1;
        #pragma unroll
        for (int e = 0; e < 8; ++e) {
            const float2 wv = *(const float2*)(weight + ((size_t)((o * 64 + k0 + e) * 24 + s) << 1));
            vd[e] = f2bf(wv.x - wv.y);
            v1[e] = f2bf(wv.y);
        }
        const int lane_f = (o & 15) | (((k0 >> 3) & 3) << 4);
        const int sub = ((o >> 4) * 2 + (k0 >> 5)) * 512 + lane_f * 8;
        *(bf16x8*)&Wfrag[(size_t)s * 4096 + sub] = vd;          // p=0: Wd
        *(bf16x8*)&Wfrag[(size_t)(24 + s) * 4096 + sub] = v1;   // p=1: W1
    } else {
        const int b = blk - 24;
        const float4* xg = (const float4*)(x + (size_t)b * 9216);
        float4* x4 = (float4*)xs;
        for (int idx = t; idx < 2304; idx += 512) x4[idx] = xg[idx];
        __syncthreads();
        #pragma unroll
        for (int u = 0; u < 3; ++u) {
            const int idx = t + u * 512;
            const float* p = xs + idx * 6;
            Ss[idx] = ((p[0] + p[1]) + (p[2] + p[3])) + (p[4] + p[5]);
        }
        __syncthreads();
        // 1152 x-chunks (6 d-rows x 192) + 192 S-chunks
        for (int cid = t; cid < 1344; cid += 512) {
            if (cid < 1152) {
                const int d = cid / 192;
                const int kk = (cid - d * 192) * 8;
                bf16x8 v;
                #pragma unroll
                for (int e = 0; e < 8; ++e) v[e] = f2bf(xs[(kk + e) * 6 + d]);
                const int n = b * 6 + d;
                const int lane_f = (n & 15) | (((kk >> 3) & 3) << 4);
                *(bf16x8*)&BfragX[(size_t)((n >> 4) * 48 + (kk >> 5)) * 512 + lane_f * 8] = v;
            } else {
                const int kk = (cid - 1152) * 8;
                bf16x8 v;
                #pragma unroll
                for (int e = 0; e < 8; ++e) v[e] = f2bf(Ss[kk + e]);
                const int lane_f = (b & 15) | (((kk >> 3) & 3) << 4);
                *(bf16x8*)&Sfrag[(size_t)((b >> 4) * 48 + (kk >> 5)) * 512 + lane_f * 8] = v;
            }
        }
    }
}

// ---------------- T-GEMM: T[m][b] = W1-part, M=1536 N=64 K=1536 ----------------
__global__ __launch_bounds__(512, 4) void tgemm_kernel(const short* __restrict__ Wfrag,
                                                       const short* __restrict__ Sfrag,
                                                       const int* __restrict__ sp,
                                                       float* __restrict__ T) {
    __shared__ __align__(16) float Red[8][64][16];   // 32 KB

    const int tid = threadIdx.x;
    const int lane = tid & 63;
    const int w = tid >> 6;

    const int bx = (int)blockIdx.x;
    const int mt = bx % 48;
    const int bt = bx / 48;           // 0..1
    const int i  = mt >> 1;
    const int o0 = (mt & 1) * 32;
    const int n0 = bt * 32;

    const int jbase = w * 3;          // 8 waves x 3 j = 24
    int sidx[3];
    #pragma unroll
    for (int t_ = 0; t_ < 3; ++t_) sidx[t_] = sp[i * 24 + jbase + t_];

    const size_t abase0 = (size_t)24 * 4096 + (size_t)(o0 >> 4) * 1024 + lane * 8;  // p=1
    const short* bbase = Sfrag + (size_t)(n0 >> 4) * 24576 + (size_t)jbase * 1024 + lane * 8;

    f32x4 acc[2][2] = {{{0.f,0.f,0.f,0.f},{0.f,0.f,0.f,0.f}},
                       {{0.f,0.f,0.f,0.f},{0.f,0.f,0.f,0.f}}};
    bf16x8 rA[2][4], rB[2][4];

#define LOADSTEP(t_, buf)                                                       \
    {                                                                           \
        const short* ap = Wfrag + (size_t)sidx[t_] * 4096 + abase0;             \
        const short* bp = bbase + (t_) * 1024;                                  \
        _Pragma("unroll")                                                       \
        for (int f = 0; f < 4; ++f) {                                           \
            rA[buf][f] = *(const bf16x8*)(ap + f * 512);                        \
            rB[buf][f] = *(const bf16x8*)(bp + ((f >> 1) * 24576) + (f & 1) * 512); \
        }                                                                       \
    }

    LOADSTEP(0, 0)
    #pragma unroll
    for (int t_ = 0; t_ < 3; ++t_) {
        const int cur = t_ & 1;
        if (t_ < 2) LOADSTEP(t_ + 1, cur ^ 1)
        #pragma unroll
        for (int kc = 0; kc < 2; ++kc)
            #pragma unroll
            for (int mi = 0; mi < 2; ++mi)
                #pragma unroll
                for (int ni = 0; ni < 2; ++ni)
                    acc[mi][ni] = MFMA16(rA[cur][mi * 2 + kc], rB[cur][ni * 2 + kc], acc[mi][ni]);
    }
#undef LOADSTEP

    #pragma unroll
    for (int mi = 0; mi < 2; ++mi)
        #pragma unroll
        for (int ni = 0; ni < 2; ++ni)
            *(f32x4*)&Red[w][lane][mi * 8 + ni * 4] = acc[mi][ni];
    __syncthreads();

    if (tid < 256) {
        const int l  = tid & 63;
        const int g  = tid >> 6;
        const int mi = g >> 1;
        const int ni = g & 1;
        const int fb = mi * 8 + ni * 4;
        f32x4 sum = *(const f32x4*)&Red[0][l][fb];
        #pragma unroll
        for (int ww = 1; ww < 8; ++ww) sum += *(const f32x4*)&Red[ww][l][fb];

        const int b = n0 + ni * 16 + (l & 15);
        const int rb = (l >> 4) * 4;
        #pragma unroll
        for (int r = 0; r < 4; ++r) {
            const int o = o0 + mi * 16 + rb + r;
            T[(size_t)(i * 64 + o) * 64 + b] = sum[r];
        }
    }
}

// ---------------- main GEMM: M=1536 N=384 K=1536 (Wd * x) ----------------
__global__ __launch_bounds__(512, 4) void gemm_kernel(const short* __restrict__ Wfrag,
                                                      const short* __restrict__ BfragX,
                                                      const float* __restrict__ T,
                                                      const float* __restrict__ bias,
                                                      const int* __restrict__ sp,
                                                      float* __restrict__ out) {
    __shared__ __align__(16) float Red[8][64][16];   // 32 KB

    const int tid = threadIdx.x;
    const int lane = tid & 63;
    const int w = tid >> 6;

    const int bx = (int)blockIdx.x;
    const int mt = bx % 48;
    const int nt = bx / 48;           // 0..11
    const int i  = mt >> 1;
    const int o0 = (mt & 1) * 32;
    const int n0 = nt * 32;

    const int jbase = w * 3;
    int sidx[3];
    #pragma unroll
    for (int t_ = 0; t_ < 3; ++t_) sidx[t_] = sp[i * 24 + jbase + t_];

    const size_t abase0 = (size_t)(o0 >> 4) * 1024 + lane * 8;   // p=0 panels
    const short* bbase = BfragX + (size_t)(n0 >> 4) * 24576 + (size_t)jbase * 1024 + lane * 8;

    f32x4 acc[2][2] = {{{0.f,0.f,0.f,0.f},{0.f,0.f,0.f,0.f}},
                       {{0.f,0.f,0.f,0.f},{0.f,0.f,0.f,0.f}}};
    bf16x8 rA[2][4], rB[2][4];

#define LOADSTEP(t_, buf)                                                       \
    {                                                                           \
        const short* ap = Wfrag + (size_t)sidx[t_] * 4096 + abase0;             \
        const short* bp = bbase + (t_) * 1024;                                  \
        _Pragma("unroll")                                                       \
        for (int f = 0; f < 4; ++f) {                                           \
            rA[buf][f] = *(const bf16x8*)(ap + f * 512);                        \
            rB[buf][f] = *(const bf16x8*)(bp + ((f >> 1) * 24576) + (f & 1) * 512); \
        }                                                                       \
    }

    LOADSTEP(0, 0)
    #pragma unroll
    for (int t_ = 0; t_ < 3; ++t_) {
        const int cur = t_ & 1;
        if (t_ < 2) LOADSTEP(t_ + 1, cur ^ 1)
        #pragma unroll
        for (int kc = 0; kc < 2; ++kc)
            #pragma unroll
            for (int mi = 0; mi < 2; ++mi)
                #pragma unroll
                for (int ni = 0; ni < 2; ++ni)
                    acc[mi][ni] = MFMA16(rA[cur][mi * 2 + kc], rB[cur][ni * 2 + kc], acc[mi][ni]);
    }
#undef LOADSTEP

    #pragma unroll
    for (int mi = 0; mi < 2; ++mi)
        #pragma unroll
        for (int ni = 0; ni < 2; ++ni)
            *(f32x4*)&Red[w][lane][mi * 8 + ni * 4] = acc[mi][ni];
    __syncthreads();

    if (tid < 256) {
        const int l  = tid & 63;
        const int g  = tid >> 6;
        const int mi = g >> 1;
        const int ni = g & 1;
        const int fb = mi * 8 + ni * 4;
        f32x4 sum = *(const f32x4*)&Red[0][l][fb];
        #pragma unroll
        for (int ww = 1; ww < 8; ++ww) sum += *(const f32x4*)&Red[ww][l][fb];

        // C/D layout: col = lane&15, row = (lane>>4)*4 + r  [verified r2-r5]
        const int col = n0 + ni * 16 + (l & 15);
        const int b = col / 6;
        const int d = col - b * 6;
        const int rb = (l >> 4) * 4;
        #pragma unroll
        for (int r = 0; r < 4; ++r) {
            const int o = o0 + mi * 16 + rb + r;
            const int m = i * 64 + o;
            out[((size_t)(b * 24 + i)) * 384 + o * 6 + d] = sum[r] + T[(size_t)m * 64 + b] + bias[o];
        }
    }
}

extern "C" void kernel_launch(void* const* d_in, const int* in_sizes, int n_in,
                              void* d_out, int out_size, void* d_ws, size_t ws_size,
                              hipStream_t stream) {
    const float* x      = (const float*)d_in[0];
    const float* weight = (const float*)d_in[1];
    const float* bias   = (const float*)d_in[2];
    const int*   sp     = (const int*)d_in[3];
    // d_in[4] = co_orbit: folded into the (d != c) factorization.

    short* Wfrag  = (short*)d_ws;                     // 2*24*4096      = 196608 bf16
    short* BfragX = Wfrag + 196608;                   // 384*1536       = 589824 bf16
    short* Sfrag  = BfragX + 589824;                  // 64*1536        =  98304 bf16
    float* T      = (float*)(Sfrag + 98304);          // 1536*64        =  98304 f32

    prep_kernel<<<88, 512, 0, stream>>>(weight, x, Wfrag, BfragX, Sfrag);
    tgemm_kernel<<<96, 512, 0, stream>>>(Wfrag, Sfrag, sp, T);
    gemm_kernel<<<576, 512, 0, stream>>>(Wfrag, BfragX, T, bias, sp, (float*)d_out);
}